// Round 11
// baseline (91.602 us; speedup 1.0000x reference)
//
#include <hip/hip_runtime.h>

#define BATCH 4
#define NPTS 8192
#define TPB 256
#define TOTAL (2 * BATCH * NPTS)    // 65536 min slots
#define PK_USH 16                   // 32 B per packed point
#define GRID (8 * (NPTS / 64))      // 8 sides x 128 colgroups = 1024 blocks

#define MINBUF_BYTES ((size_t)TOTAL * 4)                  // 256 KB
#define SIDE_BYTES ((size_t)8 * NPTS * PK_USH * 2)        // 2 MB per role array
#define REQ_WS (MINBUF_BYTES + 2 * SIDE_BYTES)            // ~4.25 MB

typedef short bf16x8 __attribute__((ext_vector_type(8)));
typedef float f32x16 __attribute__((ext_vector_type(16)));

__device__ __forceinline__ unsigned short b16(float f) {   // fp32 -> bf16 RNE
  unsigned u = __float_as_uint(f);
  return (unsigned short)((u + 0x7FFFu + ((u >> 16) & 1u)) >> 16);
}
__device__ __forceinline__ float b2f(unsigned short h) {
  return __uint_as_float(((unsigned)h) << 16);
}

// Packed K=16 rows (R8/R10-verified exact, absmax 0.0):
//  roleA(x): [(-2x)h(3), (-2x)l(3), (-2x)h(3), x2h, x2l, 1,   1,  0,0,0]
//  roleB(y): [yh(3),     yh(3),     yl(3),     1,   1, y2h, y2l, 0,0,0]
// roleA . roleB = full squared distance minus (-2x)l.yl (~1e-5).
__device__ __forceinline__ void pack_point(unsigned short* dst, float cx,
                                           float cy, float cz, bool roleA) {
  float n2 = cx * cx + cy * cy + cz * cz;
  float vx = roleA ? -2.f * cx : cx;
  float vy = roleA ? -2.f * cy : cy;
  float vz = roleA ? -2.f * cz : cz;
  unsigned hx = b16(vx), hy = b16(vy), hz = b16(vz);
  unsigned lx = b16(vx - b2f(hx)), ly = b16(vy - b2f(hy)), lz = b16(vz - b2f(hz));
  unsigned nh = b16(n2), nl = b16(n2 - b2f(nh));
  const unsigned ONE = 0x3F80u;
  uint4 lo, hi;
  if (roleA) {
    lo = make_uint4(hx | (hy << 16), hz | (lx << 16), ly | (lz << 16), hx | (hy << 16));
    hi = make_uint4(hz | (nh << 16), nl | (ONE << 16), ONE, 0u);
  } else {
    lo = make_uint4(hx | (hy << 16), hz | (hx << 16), hy | (hz << 16), lx | (ly << 16));
    hi = make_uint4(lz | (ONE << 16), ONE | (nh << 16), nl, 0u);
  }
  *(uint4*)(dst) = lo;
  *(uint4*)(dst + 8) = hi;
}

// Pre-pass: per (side=dir*4+b, point r):
//  rowpk[side] = roleA pack of that side's chamfer-B source (rows, min'ed away)
//  colpk[side] = roleB pack of that side's chamfer-A source (cols = output slots)
__global__ __launch_bounds__(TPB) void pack_pts(
    const float* __restrict__ pred, const float* __restrict__ gt,
    unsigned short* __restrict__ rowpk, unsigned short* __restrict__ colpk) {
  int idx = blockIdx.x * TPB + threadIdx.x;   // 0 .. 65535
  int side = idx >> 13, r = idx & 8191;
  int dir = side >> 2, b = side & 3;
  const float* As = (dir ? gt : pred) + ((size_t)b * NPTS + r) * 3;  // A-side
  const float* Bs = (dir ? pred : gt) + ((size_t)b * NPTS + r) * 3;  // B-side
  size_t o = ((size_t)side * NPTS + r) * PK_USH;
  pack_point(rowpk + o, Bs[0], Bs[1], Bs[2], true);
  pack_point(colpk + o, As[0], As[1], As[2], false);
}

// Owner-exclusive NN pass: ZERO atomics. Block owns 64 A-cols (2 col-sets);
// its 4 waves split the 8192 B-rows 4-ways (64 rowtiles each), streaming
// roleA frags straight from L2-resident rowpk (2 MB/role). Row-axis min is
// in-lane (C/D rows live in regs+g: col=lane&31, row=(reg&3)+8*(reg>>2)+4g —
// R10-verified, absmax 0.0), so each wave carries just 2 scalar accumulators.
// Epilogue: shfl_xor(32) g-half merge -> 1 KB LDS 4-wave min -> 64 plain
// coalesced stores. minbuf is poison-independent (every slot written once).
__global__ __launch_bounds__(TPB) void chamfer_mfma(
    const unsigned short* __restrict__ rowpk,
    const unsigned short* __restrict__ colpk,
    unsigned* __restrict__ minbuf) {
  __shared__ float sM[4][64];

  int t = threadIdx.x;
  int blk = blockIdx.x;
  int cg   = blk & 127;               // 128 colgroups of 64 cols
  int side = blk >> 7;                // 8 sides
  int w = t >> 6, lane = t & 63, g = lane >> 5, n = lane & 31;

  // Resident col-operands: 2 tiles of 32 A-points (roleB frags).
  const unsigned short* Cp = colpk + ((size_t)side * NPTS + cg * 64) * PK_USH;
  bf16x8 af0 = *(const bf16x8*)(Cp + (size_t)n * PK_USH + g * 8);
  bf16x8 af1 = *(const bf16x8*)(Cp + (size_t)(32 + n) * PK_USH + g * 8);

  // Stream this wave's 64 B-rowtiles; min-reduce rows in-lane immediately.
  const unsigned short* Rp = rowpk + ((size_t)side * NPTS + w * 2048) * PK_USH;
  const f32x16 Z = {0.f,0.f,0.f,0.f,0.f,0.f,0.f,0.f,0.f,0.f,0.f,0.f,0.f,0.f,0.f,0.f};
  float m0 = 3.4e38f, m1 = 3.4e38f;
  #pragma unroll 4
  for (int rt = 0; rt < 64; ++rt) {
    bf16x8 bf = *(const bf16x8*)(Rp + (size_t)(rt * 32 + n) * PK_USH + g * 8);
    f32x16 d0 = __builtin_amdgcn_mfma_f32_32x32x16_bf16(bf, af0, Z, 0, 0, 0);
    f32x16 d1 = __builtin_amdgcn_mfma_f32_32x32x16_bf16(bf, af1, Z, 0, 0, 0);
    #pragma unroll
    for (int r = 0; r < 16; r += 2) {
      m0 = fminf(fminf(m0, d0[r]), d0[r + 1]);   // v_min3_f32
      m1 = fminf(fminf(m1, d1[r]), d1[r + 1]);
    }
  }
  m0 = fminf(m0, __shfl_xor(m0, 32, 64));   // merge g=0/1 row halves
  m1 = fminf(m1, __shfl_xor(m1, 32, 64));

  if (lane < 32) { sM[w][n] = m0; sM[w][32 + n] = m1; }
  __syncthreads();
  if (t < 64) {
    float v = fminf(fminf(sM[0][t], sM[1][t]), fminf(sM[2][t], sM[3][t]));
    minbuf[(size_t)side * NPTS + cg * 64 + t] = __float_as_uint(fmaxf(v, 0.f));
  }
}

// ---- fallback (R8-style, self-contained, atomicMin + poison sentinel) ----
#define MCOL 258
__global__ __launch_bounds__(TPB) void chamfer_mfma_lds(
    const float* __restrict__ pred, const float* __restrict__ gt,
    unsigned* __restrict__ minbuf) {
  __shared__ __align__(16) unsigned short smem[30720];
  int blk = blockIdx.x;
  int split  = blk & 7;   blk >>= 3;
  int rowblk = blk & 31;  blk >>= 5;
  int b      = blk & 3;   blk >>= 2;
  int dir    = blk;
  const float* Ab = (dir ? gt : pred) + (size_t)b * NPTS * 3;
  const float* Bb = (dir ? pred : gt) + (size_t)b * NPTS * 3;
  int t = threadIdx.x;
  {
    int gi = rowblk * 256 + t;
    pack_point(smem + t * 24, Ab[gi * 3], Ab[gi * 3 + 1], Ab[gi * 3 + 2], true);
    #pragma unroll
    for (int k = 0; k < 4; ++k) {
      int j = t + k * TPB;
      int gj = split * 1024 + j;
      pack_point(smem + 6144 + j * 24, Bb[gj * 3], Bb[gj * 3 + 1], Bb[gj * 3 + 2], false);
    }
  }
  __syncthreads();
  int w = t >> 6, lane = t & 63;
  int g = lane >> 5, n = lane & 31;
  bf16x8 af0 = *(const bf16x8*)(smem + (w * 64 + n) * 24 + g * 8);
  bf16x8 af1 = *(const bf16x8*)(smem + (w * 64 + 32 + n) * 24 + g * 8);
  float mn0[16], mn1[16];
  #pragma unroll
  for (int r = 0; r < 16; ++r) { mn0[r] = 3.4e38f; mn1[r] = 3.4e38f; }
  const f32x16 z = {0.f,0.f,0.f,0.f,0.f,0.f,0.f,0.f,0.f,0.f,0.f,0.f,0.f,0.f,0.f,0.f};
  const unsigned short* sB = smem + 6144;
  #pragma unroll 2
  for (int c = 0; c < 32; c += 2) {
    bf16x8 bf0 = *(const bf16x8*)(sB + (c * 32 + n) * 24 + g * 8);
    bf16x8 bf1 = *(const bf16x8*)(sB + ((c + 1) * 32 + n) * 24 + g * 8);
    f32x16 a00 = __builtin_amdgcn_mfma_f32_32x32x16_bf16(af0, bf0, z, 0, 0, 0);
    f32x16 a01 = __builtin_amdgcn_mfma_f32_32x32x16_bf16(af0, bf1, z, 0, 0, 0);
    f32x16 a10 = __builtin_amdgcn_mfma_f32_32x32x16_bf16(af1, bf0, z, 0, 0, 0);
    f32x16 a11 = __builtin_amdgcn_mfma_f32_32x32x16_bf16(af1, bf1, z, 0, 0, 0);
    #pragma unroll
    for (int r = 0; r < 16; ++r) {
      mn0[r] = fminf(fminf(mn0[r], a00[r]), a01[r]);
      mn1[r] = fminf(fminf(mn1[r], a10[r]), a11[r]);
    }
  }
  __syncthreads();
  float* sM = (float*)smem;
  #pragma unroll
  for (int q = 0; q < 4; ++q) {
    int row0 = w * 64 + q * 8 + 4 * g;
    *(float2*)(sM + n * MCOL + row0)      = make_float2(mn0[q*4],   mn0[q*4+1]);
    *(float2*)(sM + n * MCOL + row0 + 2)  = make_float2(mn0[q*4+2], mn0[q*4+3]);
    *(float2*)(sM + n * MCOL + row0 + 32) = make_float2(mn1[q*4],   mn1[q*4+1]);
    *(float2*)(sM + n * MCOL + row0 + 34) = make_float2(mn1[q*4+2], mn1[q*4+3]);
  }
  __syncthreads();
  float m = 3.4e38f;
  #pragma unroll 8
  for (int c = 0; c < 32; ++c) m = fminf(m, sM[c * MCOL + t]);
  unsigned* slot = minbuf + ((size_t)dir * BATCH + b) * NPTS + rowblk * 256 + t;
  atomicMin(slot, __float_as_uint(fmaxf(m, 0.f)));
}

// Final reduction: sum all TOTAL mins, scale, write scalar out.
__global__ __launch_bounds__(1024) void chamfer_reduce(
    const unsigned* __restrict__ minbuf, float* __restrict__ out) {
  int t = threadIdx.x;
  float s = 0.f;
  const uint4* mb4 = (const uint4*)minbuf;
  #pragma unroll 4
  for (int i = t; i < TOTAL / 4; i += 1024) {
    uint4 v = mb4[i];
    s += __uint_as_float(v.x) + __uint_as_float(v.y) +
         __uint_as_float(v.z) + __uint_as_float(v.w);
  }
  #pragma unroll
  for (int off = 32; off > 0; off >>= 1) s += __shfl_down(s, off, 64);
  __shared__ float wsum[16];
  int wave = t >> 6, lane = t & 63;
  if (lane == 0) wsum[wave] = s;
  __syncthreads();
  if (t == 0) {
    float tot = 0.f;
    #pragma unroll
    for (int w = 0; w < 16; ++w) tot += wsum[w];
    out[0] = tot * (1.f / (float)(BATCH * NPTS));
  }
}

extern "C" void kernel_launch(void* const* d_in, const int* in_sizes, int n_in,
                              void* d_out, int out_size, void* d_ws, size_t ws_size,
                              hipStream_t stream) {
  const float* pred = (const float*)d_in[0];
  const float* gt   = (const float*)d_in[1];
  float* out        = (float*)d_out;
  unsigned* minbuf  = (unsigned*)d_ws;
  unsigned short* rowpk = (unsigned short*)((char*)d_ws + MINBUF_BYTES);
  unsigned short* colpk = (unsigned short*)((char*)d_ws + MINBUF_BYTES + SIDE_BYTES);

  if (ws_size >= REQ_WS) {
    pack_pts<<<dim3(TOTAL / TPB), dim3(TPB), 0, stream>>>(pred, gt, rowpk, colpk);
    chamfer_mfma<<<dim3(GRID), dim3(TPB), 0, stream>>>(rowpk, colpk, minbuf);
  } else {
    chamfer_mfma_lds<<<dim3(2048), dim3(TPB), 0, stream>>>(pred, gt, minbuf);
  }
  chamfer_reduce<<<dim3(1), dim3(1024), 0, stream>>>(minbuf, out);
}

// Round 12
// 75.918 us; speedup vs baseline: 1.2066x; 1.2066x over previous
//
#include <hip/hip_runtime.h>

#define BATCH 4
#define NPTS 8192
#define TPB 256
#define RSPLIT 4                    // row-split partial-min slices (no atomics)
#define TOTAL (2 * BATCH * NPTS)    // 65536 output slots
#define GRID (8 * 32 * RSPLIT)      // sides x colgroups x rowsplit = 1024 blocks

typedef short bf16x8 __attribute__((ext_vector_type(8)));
typedef float f32x16 __attribute__((ext_vector_type(16)));

__device__ __forceinline__ unsigned short b16(float f) {   // fp32 -> bf16 RNE
  unsigned u = __float_as_uint(f);
  return (unsigned short)((u + 0x7FFFu + ((u >> 16) & 1u)) >> 16);
}
__device__ __forceinline__ float b2f(unsigned short h) {
  return __uint_as_float(((unsigned)h) << 16);
}

// K=16 packed rows (R8/R10/R11-verified exact, absmax 0.0):
//  roleA(x): [(-2x)h(3), (-2x)l(3), (-2x)h(3), x2h, x2l, 1,   1,  0,0,0]
//  roleB(y): [yh(3),     yh(3),     yl(3),     1,   1, y2h, y2l, 0,0,0]
// roleA.roleB = squared distance minus (-2x)l.yl (~1e-5 << 9.3e-4 threshold).
// Emits the two 16B frag-halves (h=0: k0..7, h=1: k8..15).
__device__ __forceinline__ void pack_halves(uint4* lo, uint4* hi, float cx,
                                            float cy, float cz, bool roleA) {
  float n2 = cx * cx + cy * cy + cz * cz;
  float vx = roleA ? -2.f * cx : cx;
  float vy = roleA ? -2.f * cy : cy;
  float vz = roleA ? -2.f * cz : cz;
  unsigned hx = b16(vx), hy = b16(vy), hz = b16(vz);
  unsigned lx = b16(vx - b2f(hx)), ly = b16(vy - b2f(hy)), lz = b16(vz - b2f(hz));
  unsigned nh = b16(n2), nl = b16(n2 - b2f(nh));
  const unsigned ONE = 0x3F80u;
  if (roleA) {
    *lo = make_uint4(hx | (hy << 16), hz | (lx << 16), ly | (lz << 16), hx | (hy << 16));
    *hi = make_uint4(hz | (nh << 16), nl | (ONE << 16), ONE, 0u);
  } else {
    *lo = make_uint4(hx | (hy << 16), hz | (hx << 16), hy | (hz << 16), lx | (ly << 16));
    *hi = make_uint4(lz | (ONE << 16), ONE | (nh << 16), nl, 0u);
  }
}

// Self-contained NN pass: no pre-pack, no atomics, conflict-free LDS.
// Block = (side, colgroup of 256 A-cols, row-quarter of 2048 B-rows).
// LDS frag layout is LANE-ORDERED: 16B unit u = rowtile*64 + mfma_lane, so
// packer writes (thread t owns points {t, 256+t}) and reader ds_read_b128
// are both lane-stride-1 => 2-way bank alias max (free, m136).
// Row-axis min is in-lane (C/D: col=lane&31, row=(reg&3)+8*(reg>>2)+4*g;
// R10/R11-verified): 2 scalar accumulators/wave, shfl_xor(32) merge,
// plain coalesced stores into per-rowquarter partial slices.
__global__ __launch_bounds__(TPB, 4) void chamfer_nn(
    const float* __restrict__ pred, const float* __restrict__ gt,
    float* __restrict__ partial, float* __restrict__ out) {
  __shared__ __align__(16) unsigned short sA[256 * 16];   // 8 KB col frags
  __shared__ __align__(16) unsigned short sB[512 * 16];   // 16 KB row-chunk frags

  int blk = blockIdx.x;
  int rq   = blk & (RSPLIT - 1);      // row quarter
  int cg   = (blk >> 2) & 31;         // colgroup (256 cols)
  int side = blk >> 7;                // dir*4 + b
  int dir = side >> 2, b = side & 3;

  const float* As = (dir ? gt : pred) + (size_t)b * NPTS * 3;  // cols (outputs)
  const float* Bs = (dir ? pred : gt) + (size_t)b * NPTS * 3;  // rows (min'ed)

  int t = threadIdx.x;
  if (blk == 0 && t == 0) out[0] = 0.f;   // zero accumulator for reduce pass

  // Pack this block's 256 A-cols (1/thread) into lane-ordered sA.
  {
    int gp = cg * 256 + t;
    uint4 lo, hi;
    pack_halves(&lo, &hi, As[gp * 3], As[gp * 3 + 1], As[gp * 3 + 2], false);
    unsigned short* u0 = sA + ((t >> 5) * 64 + (t & 31)) * 8;
    *(uint4*)u0 = lo;
    *(uint4*)(u0 + 32 * 8) = hi;
  }
  __syncthreads();

  int w = t >> 6, lane = t & 63;
  // Resident col-operands: wave w owns col-tiles 2w, 2w+1.
  bf16x8 af0 = *(const bf16x8*)(sA + ((2 * w) * 64 + lane) * 8);
  bf16x8 af1 = *(const bf16x8*)(sA + ((2 * w + 1) * 64 + lane) * 8);

  const f32x16 Z = {0.f,0.f,0.f,0.f,0.f,0.f,0.f,0.f,0.f,0.f,0.f,0.f,0.f,0.f,0.f,0.f};
  float m0 = 3.4e38f, m1 = 3.4e38f;
  int rowbase = rq * 2048;

  #pragma unroll 1
  for (int c = 0; c < 4; ++c) {       // 4 chunks of 512 rows
    // Pack 2 rows/thread ({t, 256+t}: keeps ds_write lane-stride 1).
    #pragma unroll
    for (int h = 0; h < 2; ++h) {
      int p = h * 256 + t;            // local row in chunk
      int gp = rowbase + c * 512 + p;
      uint4 lo, hi;
      pack_halves(&lo, &hi, Bs[gp * 3], Bs[gp * 3 + 1], Bs[gp * 3 + 2], true);
      unsigned short* u0 = sB + ((p >> 5) * 64 + (p & 31)) * 8;
      *(uint4*)u0 = lo;
      *(uint4*)(u0 + 32 * 8) = hi;
    }
    __syncthreads();
    // 16 rowtiles: 1 lane-sequential ds_read_b128 + 2 MFMA + 16 min3 each.
    #pragma unroll 4
    for (int rt = 0; rt < 16; ++rt) {
      bf16x8 bf = *(const bf16x8*)(sB + (rt * 64 + lane) * 8);
      f32x16 d0 = __builtin_amdgcn_mfma_f32_32x32x16_bf16(bf, af0, Z, 0, 0, 0);
      f32x16 d1 = __builtin_amdgcn_mfma_f32_32x32x16_bf16(bf, af1, Z, 0, 0, 0);
      #pragma unroll
      for (int r = 0; r < 16; r += 2) {
        m0 = fminf(fminf(m0, d0[r]), d0[r + 1]);   // v_min3_f32
        m1 = fminf(fminf(m1, d1[r]), d1[r + 1]);
      }
    }
    __syncthreads();                  // sB reads done before next pack
  }

  m0 = fminf(m0, __shfl_xor(m0, 32, 64));   // merge complementary row halves
  m1 = fminf(m1, __shfl_xor(m1, 32, 64));
  if (lane < 32) {
    float* dst = partial + (size_t)rq * TOTAL + (size_t)side * NPTS + cg * 256;
    dst[w * 64 + lane]      = fmaxf(m0, 0.f);
    dst[w * 64 + 32 + lane] = fmaxf(m1, 0.f);
  }
}

// Reduce: min over RSPLIT partials per slot, block-sum, one atomicAdd/block.
// out[0] was zeroed by chamfer_nn (stream-ordered before this kernel).
__global__ __launch_bounds__(TPB) void chamfer_reduce(
    const float* __restrict__ partial, float* __restrict__ out) {
  int t = threadIdx.x;
  int s = blockIdx.x * TPB + t;       // slot 0..65535
  float v = partial[s];
  #pragma unroll
  for (int r = 1; r < RSPLIT; ++r)
    v = fminf(v, partial[(size_t)r * TOTAL + s]);
  #pragma unroll
  for (int off = 32; off > 0; off >>= 1) v += __shfl_down(v, off, 64);
  __shared__ float wsum[4];
  int wave = t >> 6, lane = t & 63;
  if (lane == 0) wsum[wave] = v;
  __syncthreads();
  if (t == 0) {
    float tot = (wsum[0] + wsum[1]) + (wsum[2] + wsum[3]);
    atomicAdd(out, tot * (1.f / (float)(BATCH * NPTS)));
  }
}

extern "C" void kernel_launch(void* const* d_in, const int* in_sizes, int n_in,
                              void* d_out, int out_size, void* d_ws, size_t ws_size,
                              hipStream_t stream) {
  const float* pred = (const float*)d_in[0];
  const float* gt   = (const float*)d_in[1];
  float* out        = (float*)d_out;
  float* partial    = (float*)d_ws;   // RSPLIT x 65536 floats = 1 MB

  chamfer_nn<<<dim3(GRID), dim3(TPB), 0, stream>>>(pred, gt, partial, out);
  chamfer_reduce<<<dim3(TOTAL / TPB), dim3(TPB), 0, stream>>>(partial, out);
}